// Round 5
// baseline (221.795 us; speedup 1.0000x reference)
//
#include <hip/hip_runtime.h>
#include <math.h>

#define BN_EPS 1e-5f

using short8  = __attribute__((ext_vector_type(8))) short;
using f32x16  = __attribute__((ext_vector_type(16))) float;

// ---------------------------------------------------------------------------
// x (16,640,32,32) fp32. Pixels P=16384, p = b*1024 + h*32 + w.
// ident: bf16 [p][64] pixel-major.
// feat K-order (permuted): kg'<64 -> identity ch kg'; kg'>=64: t=kg'-64,
//   ksp=t>>6 (spatial 0..24), c=t&63; orig w_emb col = 64 + c*25 + ksp.
// Weight tiles (A-frag order), per kc (K=32 chunk) 512 uint4 units:
//   u = (mf*2+kh)*64 + sl;  oc = mt*128 + mf*32 + (sl&31),
//   k = kc*32 + kh*16 + (sl>>5)*8 + j
// 32-px B-frag unit order (per kc, 128 units):
//   u = (bkh<<6)|sl; px = sl&31, kg' = kc*32 + bkh*16 + (sl>>5)*8 + j
//
// k_fused v2 (feat+emb+out, 32-px tiles): grid 512 (one block per image ROW),
// 640 thr = 10 waves, wave w owns oc [64w,64w+64) for both GEMMs.
// LDS 79.8 KB -> 2 blocks/CU (20 waves/CU, 5/SIMD): cross-block overlap is
// the latency-hiding mechanism (4 rounds of counters show the GEMM phases
// are latency-bound at 1 block/CU; traffic is already minimal+L2-resident).
// Phase 0: ident slab 5x36 halo -> LDS, invD, ctrs.
// Phase 1: emb GEMM, 26 chunks of 2 kc, gen->stg double-buffered; gen is
//   done by threads<256 (waves 0-3) while waves 4-9 go straight to MFMA.
// Phase 2: bias+relu -> Ep[20][128] (out-GEMM B-frag).
// Phase 3: out GEMM (B=Ep, A=wOt L2-res), direct fp32 stores.
// LDS: 25920 slab + 4608 ctrs + 128 invD + 8192 stg + 40960 Ep = 79808 B.
// ---------------------------------------------------------------------------

__device__ __forceinline__ float bflo(unsigned u) { return __uint_as_float(u << 16); }
__device__ __forceinline__ float bfhi(unsigned u) { return __uint_as_float(u & 0xffff0000u); }

__device__ __forceinline__ unsigned bf16_rne(float f) {
    unsigned u = __float_as_uint(f);
    return (u + 0x7fffu + ((u >> 16) & 1u)) >> 16;
}
__device__ __forceinline__ unsigned pack_bf16(float lo, float hi) {
    return bf16_rne(lo) | (bf16_rne(hi) << 16);
}
__device__ __forceinline__ unsigned pk_hu(float lo, float hi) {
    unsigned a = __float_as_uint(lo) + 0x8000u;
    unsigned b = __float_as_uint(hi) + 0x8000u;
    return __builtin_amdgcn_perm(b, a, 0x07060302u);
}
__device__ __forceinline__ unsigned pmul_fast(unsigned a, unsigned b) {
    return pk_hu(bflo(a) * bflo(b), bfhi(a) * bfhi(b));
}

// ===========================================================================
// k_prepAll: blocks [0,640) build wEt (per-oc row staging);
//            blocks [640,872) do scalars + wIt + wOt.
// ===========================================================================
__global__ __launch_bounds__(256)
void k_prepAll(const float* __restrict__ g1, const float* __restrict__ b1,
               const float* __restrict__ m1, const float* __restrict__ v1,
               const float* __restrict__ w_in,
               const float* __restrict__ gi, const float* __restrict__ bi,
               const float* __restrict__ mi, const float* __restrict__ vi,
               const float* __restrict__ w_emb,
               const float* __restrict__ ge, const float* __restrict__ be,
               const float* __restrict__ me, const float* __restrict__ ve,
               const float* __restrict__ w_out,
               const float* __restrict__ go, const float* __restrict__ bo,
               const float* __restrict__ mo, const float* __restrict__ vo,
               float* __restrict__ s1, float* __restrict__ b1c,
               float* __restrict__ biasI, float* __restrict__ biasE, float* __restrict__ biasO,
               unsigned* __restrict__ wIt, unsigned* __restrict__ wEt, unsigned* __restrict__ wOt)
{
    __shared__ float row[1664];
    const int tid = threadIdx.x;

    if (blockIdx.x < 640) {
        const int oc = blockIdx.x;
#pragma unroll
        for (int it = 0; it < 2; it++) {
            int u = it * 256 + tid;
            if (u < 416)
                ((float4*)row)[u] = ((const float4*)&w_emb[(size_t)oc * 1664])[u];
        }
        __syncthreads();
        if (tid < 208) {
            int kc = tid >> 2, kh = (tid >> 1) & 1, ksub = tid & 1;
            int k0 = kc * 32 + kh * 16 + ksub * 8;
            float sc = ge[oc] * rsqrtf(ve[oc] + BN_EPS);
            float v[8];
#pragma unroll
            for (int j = 0; j < 8; j++) {
                int kgp = k0 + j;
                int orig;
                if (kgp < 64) orig = kgp;
                else { int t = kgp - 64; orig = 64 + (t & 63) * 25 + (t >> 6); }
                v[j] = row[orig] * sc;
            }
            int mt = oc >> 7, mf = (oc >> 5) & 3;
            int idx = (mt * 52 + kc) * 512 + (mf * 2 + kh) * 64 + ksub * 32 + (oc & 31);
            ((uint4*)wEt)[idx] = make_uint4(pack_bf16(v[0], v[1]), pack_bf16(v[2], v[3]),
                                            pack_bf16(v[4], v[5]), pack_bf16(v[6], v[7]));
        }
        return;
    }

    int i = (blockIdx.x - 640) * 256 + tid;

    if (i < 640) {
        float s = g1[i] * rsqrtf(v1[i] + BN_EPS);
        s1[i] = s; b1c[i] = b1[i] - m1[i] * s;
    } else if (i < 704) {
        int c = i - 640;
        float s = gi[c] * rsqrtf(vi[c] + BN_EPS);
        biasI[c] = bi[c] - mi[c] * s;
    } else if (i < 1344) {
        int c = i - 704;
        float s = ge[c] * rsqrtf(ve[c] + BN_EPS);
        biasE[c] = be[c] - me[c] * s;
    } else if (i < 1984) {
        int c = i - 1344;
        float s = go[c] * rsqrtf(vo[c] + BN_EPS);
        biasO[c] = bo[c] - mo[c] * s;
    }

    if (i >= 2048 && i < 7168) {         // wIt
        int u = i - 2048;
        int kc = u >> 8, w = u & 255;
        int mf = w >> 7, kh = (w >> 6) & 1, sl = w & 63;
        int oc = mf * 32 + (sl & 31);
        int k0 = kc * 32 + kh * 16 + (sl >> 5) * 8;
        float sc = gi[oc] * rsqrtf(vi[oc] + BN_EPS);
        unsigned d[4];
#pragma unroll
        for (int q = 0; q < 4; q++)
            d[q] = pack_bf16(w_in[oc * 640 + k0 + 2 * q] * sc,
                             w_in[oc * 640 + k0 + 2 * q + 1] * sc);
        ((uint4*)wIt)[u] = make_uint4(d[0], d[1], d[2], d[3]);
    }

    if (i >= 8192 && i < 59392) {        // wOt
        int u = i - 8192;
        int ci = u >> 9, w = u & 511;
        int mt = ci / 20, kc = ci - mt * 20;
        int mf = w >> 7, kh = (w >> 6) & 1, sl = w & 63;
        int oc = mt * 128 + mf * 32 + (sl & 31);
        int k0 = kc * 32 + kh * 16 + (sl >> 5) * 8;
        float sc = go[oc] * rsqrtf(vo[oc] + BN_EPS);
        unsigned d[4];
#pragma unroll
        for (int q = 0; q < 4; q++)
            d[q] = pack_bf16(w_out[oc * 640 + k0 + 2 * q] * sc,
                             w_out[oc * 640 + k0 + 2 * q + 1] * sc);
        ((uint4*)wOt)[u] = make_uint4(d[0], d[1], d[2], d[3]);
    }
}

// ===========================================================================
// k_identity: 512 thr, K-split halves + fp32 LDS reduction.
// ===========================================================================
__global__ __launch_bounds__(512, 1)
void k_identity(const float* __restrict__ x,
                const float* __restrict__ s1, const float* __restrict__ b1c,
                const unsigned* __restrict__ wIt, const float* __restrict__ biasI,
                unsigned* __restrict__ ident)
{
    __shared__ short smem[2][4096];
    __shared__ float Tpart[64 * 65];
    __shared__ float T[64 * 68];
    __shared__ float inv[64];

    const int tid  = threadIdx.x;
    const int half = tid >> 8;
    const int t    = tid & 255;
    const int l = t & 63, wv = t >> 6;
    const int mf = wv >> 1, nf = wv & 1;
    const int p0 = blockIdx.x * 64;
    const int b = p0 >> 10, hw0 = p0 & 1023;

    f32x16 acc;
#pragma unroll
    for (int r = 0; r < 16; r++) acc[r] = 0.f;

    for (int i = 0; i < 10; i++) {
        const int kc = half * 10 + i;
        uint4 av = ((const uint4*)wIt)[kc * 256 + t];
        int bnf = t >> 7, bkh = (t >> 6) & 1, sl = t & 63;
        int px = bnf * 32 + (sl & 31);
        int ch0 = kc * 32 + bkh * 16 + (sl >> 5) * 8;
        float4 sA = *(const float4*)&s1[ch0], sB = *(const float4*)&s1[ch0 + 4];
        float4 bA = *(const float4*)&b1c[ch0], bB = *(const float4*)&b1c[ch0 + 4];
        float vv[8];
        const float* xp = &x[((size_t)b * 640 + ch0) * 1024 + hw0 + px];
        vv[0] = fmaxf(fmaf(xp[0], sA.x, bA.x), 0.f);
        vv[1] = fmaxf(fmaf(xp[1024], sA.y, bA.y), 0.f);
        vv[2] = fmaxf(fmaf(xp[2048], sA.z, bA.z), 0.f);
        vv[3] = fmaxf(fmaf(xp[3072], sA.w, bA.w), 0.f);
        vv[4] = fmaxf(fmaf(xp[4096], sB.x, bB.x), 0.f);
        vv[5] = fmaxf(fmaf(xp[5120], sB.y, bB.y), 0.f);
        vv[6] = fmaxf(fmaf(xp[6144], sB.z, bB.z), 0.f);
        vv[7] = fmaxf(fmaf(xp[7168], sB.w, bB.w), 0.f);
        uint4 bvpk = make_uint4(pack_bf16(vv[0], vv[1]), pack_bf16(vv[2], vv[3]),
                                pack_bf16(vv[4], vv[5]), pack_bf16(vv[6], vv[7]));
        __syncthreads();
        ((uint4*)smem[half])[t] = av;
        ((uint4*)(smem[half] + 2048))[t] = bvpk;
        __syncthreads();
#pragma unroll
        for (int kh = 0; kh < 2; kh++) {
            short8 a  = *(const short8*)&smem[half][((mf * 2 + kh) * 64 + l) * 8];
            short8 bb = *(const short8*)&smem[half][2048 + ((nf * 2 + kh) * 64 + l) * 8];
            acc = __builtin_amdgcn_mfma_f32_32x32x16_bf16(a, bb, acc, 0, 0, 0);
        }
    }
    if (half == 1) {
#pragma unroll
        for (int r = 0; r < 16; r++) {
            int m = mf * 32 + (r & 3) + 8 * (r >> 2) + 4 * (l >> 5);
            int px = nf * 32 + (l & 31);
            Tpart[px * 65 + m] = acc[r];
        }
    }
    __syncthreads();
    if (half == 0) {
#pragma unroll
        for (int r = 0; r < 16; r++) {
            int m = mf * 32 + (r & 3) + 8 * (r >> 2) + 4 * (l >> 5);
            int px = nf * 32 + (l & 31);
            float v = acc[r] + Tpart[px * 65 + m];
            T[px * 68 + m] = fmaxf(v + biasI[m], 0.f);
        }
    }
    __syncthreads();
    if (tid < 64) {
        float sum = 0.f;
#pragma unroll 8
        for (int c = 0; c < 64; c++) { float v = T[tid * 68 + c]; sum = fmaf(v, v, sum); }
        inv[tid] = 1.f / fmaxf(sqrtf(sum), 1e-12f);
    }
    __syncthreads();
    {
        int px = tid >> 3, q = tid & 7;
        float iv = inv[px];
        unsigned d[4];
#pragma unroll
        for (int t2 = 0; t2 < 4; t2++)
            d[t2] = pack_bf16(T[px * 68 + q * 8 + 2 * t2] * iv,
                              T[px * 68 + q * 8 + 2 * t2 + 1] * iv);
        *(uint4*)&ident[(size_t)(p0 + px) * 32 + q * 4] = make_uint4(d[0], d[1], d[2], d[3]);
    }
}

// ===========================================================================
// feat B-unit generator (32-px tile): unit (kcAbs, t), t in [0,128).
// ===========================================================================
__device__ __forceinline__ uint4 gen_feat_unit32(const short* slab, const short* ctrs,
                                                 int kcAbs, int t)
{
    const int sl = t & 63;
    const int bkh = (t >> 6) & 1;
    const int px = sl & 31;
    const int cl = bkh * 16 + (sl >> 5) * 8;
    if (kcAbs < 2) {
        return *(const uint4*)&slab[(2 * 36 + px + 2) * 72 + kcAbs * 32 + cl];
    } else {
        int idx = kcAbs - 2;
        int ksp = idx >> 1;
        int cb = (idx & 1) * 32 + cl;
        int kho = ksp / 5, kwo = ksp - kho * 5;
        int spx = kho * 36 + px + kwo;
        const unsigned* nb = (const unsigned*)&slab[spx * 72 + cb];
        const unsigned* ct = (const unsigned*)&ctrs[px * 72 + cb];
        return make_uint4(pmul_fast(nb[0], ct[0]), pmul_fast(nb[1], ct[1]),
                          pmul_fast(nb[2], ct[2]), pmul_fast(nb[3], ct[3]));
    }
}

// ===========================================================================
// k_fused v2: 32-px tiles. grid 512, 640 thr = 10 waves, 2 blocks/CU.
// ===========================================================================
__global__ __launch_bounds__(640, 5)
void k_fused(const unsigned* __restrict__ ident,
             const unsigned* __restrict__ wEt, const float* __restrict__ biasE,
             const unsigned* __restrict__ wOt, const float* __restrict__ biasO,
             float* __restrict__ out)
{
    __shared__ short slab[180 * 72];     // 5x36 spx x 72 shorts (25920 B)
    __shared__ short ctrs[32 * 72];      // 32 px x 72 shorts    (4608 B)
    __shared__ float invDs[32];          // 128 B
    __shared__ char  stg[2][4096];       // 8192 B staging (2 kc x 128 uint4 each)
    __shared__ uint4 Ep[20 * 128];       // 40960 B: e in out-GEMM B-frag order

    const int tid = threadIdx.x;
    const int l = tid & 63;
    const int w = tid >> 6;              // wave 0..9, oc base = w*64
    const int mt = w >> 1, mf0 = (w & 1) * 2;
    const int b = blockIdx.x >> 5;       // image
    const int r0 = blockIdx.x & 31;      // row within image

    // ---- phase 0a: stage ident slab (5 rows x 36 cols, 2-halo) ----
#pragma unroll
    for (int it = 0; it < 3; it++) {
        int u = it * 640 + tid;
        if (u < 1440) {
            int spx = u >> 3, q = u & 7;
            int sr = spx / 36, sc = spx - sr * 36;
            int r = r0 + sr - 2, cc = sc - 2;
            uint4 v = make_uint4(0u, 0u, 0u, 0u);
            if (r >= 0 && r < 32 && cc >= 0 && cc < 32)
                v = *(const uint4*)&ident[((size_t)(b * 1024 + r * 32 + cc) * 64 + q * 8) / 2];
            *(uint4*)&slab[spx * 72 + q * 8] = v;
        }
    }
    __syncthreads();

    // ---- phase 0b: invD (featureL2Norm of corr), 32 px x 8 parts ----
    if (tid < 256) {
        int px = tid >> 3, part = tid & 7;
        float ctr[8];
        const unsigned* cp = (const unsigned*)&slab[(2 * 36 + px + 2) * 72 + part * 8];
#pragma unroll
        for (int d = 0; d < 4; d++) { ctr[2 * d] = bflo(cp[d]); ctr[2 * d + 1] = bfhi(cp[d]); }
        float sum = 0.f;
#pragma unroll
        for (int k = 0; k < 25; k++) {
            const int kh = k / 5, kw = k % 5;
            const unsigned* nb = (const unsigned*)&slab[(kh * 36 + px + kw) * 72 + part * 8];
#pragma unroll
            for (int d = 0; d < 4; d++) {
                float q0 = bflo(nb[d]) * ctr[2 * d];
                float q1 = bfhi(nb[d]) * ctr[2 * d + 1];
                sum = fmaf(q0, q0, sum); sum = fmaf(q1, q1, sum);
            }
        }
        sum += __shfl_xor(sum, 1);
        sum += __shfl_xor(sum, 2);
        sum += __shfl_xor(sum, 4);
        if (part == 0) invDs[px] = rsqrtf(sum + 1e-6f);
    }
    __syncthreads();

    // ---- phase 0c: normalized centers ----
    if (tid < 256) {
        int px = tid >> 3, q = tid & 7;
        const unsigned* src = (const unsigned*)&slab[(2 * 36 + px + 2) * 72 + q * 8];
        float iv = invDs[px];
        unsigned d[4];
#pragma unroll
        for (int dd = 0; dd < 4; dd++)
            d[dd] = pk_hu(bflo(src[dd]) * iv, bfhi(src[dd]) * iv);
        *(uint4*)&ctrs[px * 72 + q * 8] = make_uint4(d[0], d[1], d[2], d[3]);
    }
    __syncthreads();

    // ---- phase 1: emb GEMM, 26 chunks of 2 kc, gen by threads<256 ----
    const uint4* A = (const uint4*)wEt + (size_t)(mt * 52) * 512;

    f32x16 acc[2];
#pragma unroll
    for (int i = 0; i < 2; i++)
#pragma unroll
        for (int r = 0; r < 16; r++) acc[i][r] = 0.f;

    if (tid < 256) {                     // gen chunk 0 (kc 0,1)
        uint4 f = gen_feat_unit32(slab, ctrs, tid >> 7, tid & 127);
        *(uint4*)&stg[0][tid * 16] = f;
    }
    __syncthreads();

    for (int c = 0; c < 26; c++) {
        const int cur = c & 1, nxt = cur ^ 1;
        if (c < 25 && tid < 256) {       // gen next chunk while others MFMA
            int kc0 = (c + 1) * 2;
            uint4 f = gen_feat_unit32(slab, ctrs, kc0 + (tid >> 7), tid & 127);
            *(uint4*)&stg[nxt][tid * 16] = f;
        }
#pragma unroll
        for (int kcL = 0; kcL < 2; kcL++) {
            const int kc = c * 2 + kcL;
            uint4 av[2][2], bv[2];
#pragma unroll
            for (int mi = 0; mi < 2; mi++)
#pragma unroll
                for (int kh = 0; kh < 2; kh++)
                    av[mi][kh] = A[(size_t)kc * 512 + (((mf0 + mi) * 2 + kh) << 6) + l];
#pragma unroll
            for (int kh = 0; kh < 2; kh++)
                bv[kh] = *(const uint4*)&stg[cur][(kcL * 128 + (kh << 6) + l) * 16];
#pragma unroll
            for (int kh = 0; kh < 2; kh++) {
                acc[0] = __builtin_amdgcn_mfma_f32_32x32x16_bf16(*(short8*)&av[0][kh], *(short8*)&bv[kh], acc[0], 0, 0, 0);
                acc[1] = __builtin_amdgcn_mfma_f32_32x32x16_bf16(*(short8*)&av[1][kh], *(short8*)&bv[kh], acc[1], 0, 0, 0);
            }
        }
        __syncthreads();
    }

    // ---- phase 2: bias+relu epilogue into Ep (out-GEMM B-frag order) ----
    // acc[mi][rg*4+q] -> oc = w*64 + mi*32 + q + 8*rg + 4*(l>>5), px = l&31.
    // Ep unit = (2w+mi)*128 + ((rg>>1)<<6) + ((rg&1)<<5) + (l&31); uint2 half (l>>5).
#pragma unroll
    for (int mi = 0; mi < 2; mi++) {
        const int kbase = (w * 2 + mi) * 128;
#pragma unroll
        for (int rg = 0; rg < 4; rg++) {
            int ocb = w * 64 + mi * 32 + 8 * rg + 4 * (l >> 5);
            float4 bb = *(const float4*)&biasE[ocb];
            unsigned d0 = pack_bf16(fmaxf(acc[mi][rg * 4 + 0] + bb.x, 0.f),
                                    fmaxf(acc[mi][rg * 4 + 1] + bb.y, 0.f));
            unsigned d1 = pack_bf16(fmaxf(acc[mi][rg * 4 + 2] + bb.z, 0.f),
                                    fmaxf(acc[mi][rg * 4 + 3] + bb.w, 0.f));
            int unit = kbase + ((rg >> 1) << 6) + ((rg & 1) << 5) + (l & 31);
            ((uint2*)Ep)[unit * 2 + (l >> 5)] = make_uint2(d0, d1);
        }
    }
    __syncthreads();

    // ---- phase 3: out GEMM. B = Ep (LDS), A = wOt (L2). ----
    const int hw0 = r0 * 32;
    const uint4* Ao = (const uint4*)wOt + (size_t)(mt * 20) * 512;

    f32x16 acc2[2];
#pragma unroll
    for (int i = 0; i < 2; i++)
#pragma unroll
        for (int r = 0; r < 16; r++) acc2[i][r] = 0.f;

#pragma unroll 2
    for (int kc = 0; kc < 20; kc++) {
        uint4 av[2][2], bv[2];
#pragma unroll
        for (int mi = 0; mi < 2; mi++)
#pragma unroll
            for (int kh = 0; kh < 2; kh++)
                av[mi][kh] = Ao[(size_t)kc * 512 + (((mf0 + mi) * 2 + kh) << 6) + l];
#pragma unroll
        for (int kh = 0; kh < 2; kh++)
            bv[kh] = Ep[kc * 128 + (kh << 6) + l];
#pragma unroll
        for (int kh = 0; kh < 2; kh++) {
            acc2[0] = __builtin_amdgcn_mfma_f32_32x32x16_bf16(*(short8*)&av[0][kh], *(short8*)&bv[kh], acc2[0], 0, 0, 0);
            acc2[1] = __builtin_amdgcn_mfma_f32_32x32x16_bf16(*(short8*)&av[1][kh], *(short8*)&bv[kh], acc2[1], 0, 0, 0);
        }
    }

#pragma unroll
    for (int mi = 0; mi < 2; mi++) {
        int px = l & 31;
#pragma unroll
        for (int r = 0; r < 16; r++) {
            int oc = w * 64 + mi * 32 + (r & 3) + 8 * (r >> 2) + 4 * (l >> 5);
            out[((size_t)b * 640 + oc) * 1024 + hw0 + px] = acc2[mi][r] + biasO[oc];
        }
    }
}

// ===========================================================================
extern "C" void kernel_launch(void* const* d_in, const int* in_sizes, int n_in,
                              void* d_out, int out_size, void* d_ws, size_t ws_size,
                              hipStream_t stream)
{
    const float* x    = (const float*)d_in[0];
    const float* g1   = (const float*)d_in[1];
    const float* b1   = (const float*)d_in[2];
    const float* m1   = (const float*)d_in[3];
    const float* v1   = (const float*)d_in[4];
    const float* w_in = (const float*)d_in[5];
    const float* gi   = (const float*)d_in[6];
    const float* bi   = (const float*)d_in[7];
    const float* mi   = (const float*)d_in[8];
    const float* vi   = (const float*)d_in[9];
    const float* w_emb= (const float*)d_in[10];
    const float* ge   = (const float*)d_in[11];
    const float* be   = (const float*)d_in[12];
    const float* me   = (const float*)d_in[13];
    const float* ve   = (const float*)d_in[14];
    const float* w_out= (const float*)d_in[15];
    const float* go   = (const float*)d_in[16];
    const float* bo   = (const float*)d_in[17];
    const float* mo   = (const float*)d_in[18];
    const float* vo   = (const float*)d_in[19];

    char* ws = (char*)d_ws;
    float*    s1    = (float*)(ws + 0);
    float*    b1c   = (float*)(ws + 2560);
    float*    biasI = (float*)(ws + 5120);
    float*    biasE = (float*)(ws + 5376);
    float*    biasO = (float*)(ws + 7936);
    unsigned* wIt   = (unsigned*)(ws + 16384);
    unsigned* wOt   = (unsigned*)(ws + 98304);
    unsigned* wEt   = (unsigned*)(ws + 917504);
    unsigned* ident = (unsigned*)(ws + 3047424);   // ends 5,144,576
    float*    out   = (float*)d_out;

    k_prepAll<<<872, 256, 0, stream>>>(g1, b1, m1, v1, w_in, gi, bi, mi, vi,
                                       w_emb, ge, be, me, ve, w_out, go, bo, mo, vo,
                                       s1, b1c, biasI, biasE, biasO, wIt, wEt, wOt);
    k_identity<<<256, 512, 0, stream>>>(x, s1, b1c, wIt, biasI, ident);
    k_fused<<<512, 640, 0, stream>>>(ident, wEt, biasE, wOt, biasO, out);
}

// Round 6
// 196.231 us; speedup vs baseline: 1.1303x; 1.1303x over previous
//
#include <hip/hip_runtime.h>
#include <math.h>

#define BN_EPS 1e-5f

using short8  = __attribute__((ext_vector_type(8))) short;
using f32x16  = __attribute__((ext_vector_type(16))) float;

// ---------------------------------------------------------------------------
// x (16,640,32,32) fp32. Pixels P=16384, p = b*1024 + h*32 + w.
// feat K-order (permuted): kg'<64 -> identity ch kg'; kg'>=64: t=kg'-64,
//   ksp=t>>6 (spatial 0..24), c=t&63; orig w_emb col = 64 + c*25 + ksp.
// Weight tiles (A-frag order), per kc (K=32 chunk): see k_prepAll.
//
// k_mega (identity+feat+emb+out): grid 256 (one block per 64-px tile = 2
// rows), 640 thr = 10 waves, wave w owns oc [64w,64w+64) in the GEMMs.
// Phase 0a: waves 0-6 COMPUTE the 6x36-halo identity slab from x in-register
//   (replaces the former k_identity dispatch + ident HBM round-trip):
//   per wave 32 slab-px, K=640 MFMA loop, A=wIt (L2), B=relu(BN(x)) packed
//   on the fly; epilogue bias+relu+pixel-L2-norm (shfl across lane halves),
//   OOB px forced to 0, pack bf16 -> slab.
// Phase 0b/0c: invD + normalized ctrs (unchanged).
// Phase 1: emb GEMM, B-chunks generated into LDS (unchanged from r4).
// Phase 2: bias+relu -> Ep (out-GEMM B-frag). Phase 3: out GEMM -> out.
// LDS: 31104 slab + 9216 ctrs + 256 invD + 32768 stg + 81920 Ep = 155264 B.
// ---------------------------------------------------------------------------

__device__ __forceinline__ float bflo(unsigned u) { return __uint_as_float(u << 16); }
__device__ __forceinline__ float bfhi(unsigned u) { return __uint_as_float(u & 0xffff0000u); }

__device__ __forceinline__ unsigned bf16_rne(float f) {
    unsigned u = __float_as_uint(f);
    return (u + 0x7fffu + ((u >> 16) & 1u)) >> 16;
}
__device__ __forceinline__ unsigned pack_bf16(float lo, float hi) {
    return bf16_rne(lo) | (bf16_rne(hi) << 16);
}
__device__ __forceinline__ unsigned pk_hu(float lo, float hi) {
    unsigned a = __float_as_uint(lo) + 0x8000u;
    unsigned b = __float_as_uint(hi) + 0x8000u;
    return __builtin_amdgcn_perm(b, a, 0x07060302u);
}
__device__ __forceinline__ unsigned pmul_fast(unsigned a, unsigned b) {
    return pk_hu(bflo(a) * bflo(b), bfhi(a) * bfhi(b));
}

// ===========================================================================
// k_prepAll: blocks [0,640) build wEt (per-oc row staging);
//            blocks [640,872) do scalars + wIt + wOt.
// ===========================================================================
__global__ __launch_bounds__(256)
void k_prepAll(const float* __restrict__ g1, const float* __restrict__ b1,
               const float* __restrict__ m1, const float* __restrict__ v1,
               const float* __restrict__ w_in,
               const float* __restrict__ gi, const float* __restrict__ bi,
               const float* __restrict__ mi, const float* __restrict__ vi,
               const float* __restrict__ w_emb,
               const float* __restrict__ ge, const float* __restrict__ be,
               const float* __restrict__ me, const float* __restrict__ ve,
               const float* __restrict__ w_out,
               const float* __restrict__ go, const float* __restrict__ bo,
               const float* __restrict__ mo, const float* __restrict__ vo,
               float* __restrict__ s1, float* __restrict__ b1c,
               float* __restrict__ biasI, float* __restrict__ biasE, float* __restrict__ biasO,
               unsigned* __restrict__ wIt, unsigned* __restrict__ wEt, unsigned* __restrict__ wOt)
{
    __shared__ float row[1664];
    const int tid = threadIdx.x;

    if (blockIdx.x < 640) {
        const int oc = blockIdx.x;
#pragma unroll
        for (int it = 0; it < 2; it++) {
            int u = it * 256 + tid;
            if (u < 416)
                ((float4*)row)[u] = ((const float4*)&w_emb[(size_t)oc * 1664])[u];
        }
        __syncthreads();
        if (tid < 208) {
            int kc = tid >> 2, kh = (tid >> 1) & 1, ksub = tid & 1;
            int k0 = kc * 32 + kh * 16 + ksub * 8;
            float sc = ge[oc] * rsqrtf(ve[oc] + BN_EPS);
            float v[8];
#pragma unroll
            for (int j = 0; j < 8; j++) {
                int kgp = k0 + j;
                int orig;
                if (kgp < 64) orig = kgp;
                else { int t = kgp - 64; orig = 64 + (t & 63) * 25 + (t >> 6); }
                v[j] = row[orig] * sc;
            }
            int mt = oc >> 7, mf = (oc >> 5) & 3;
            int idx = (mt * 52 + kc) * 512 + (mf * 2 + kh) * 64 + ksub * 32 + (oc & 31);
            ((uint4*)wEt)[idx] = make_uint4(pack_bf16(v[0], v[1]), pack_bf16(v[2], v[3]),
                                            pack_bf16(v[4], v[5]), pack_bf16(v[6], v[7]));
        }
        return;
    }

    int i = (blockIdx.x - 640) * 256 + tid;

    if (i < 640) {
        float s = g1[i] * rsqrtf(v1[i] + BN_EPS);
        s1[i] = s; b1c[i] = b1[i] - m1[i] * s;
    } else if (i < 704) {
        int c = i - 640;
        float s = gi[c] * rsqrtf(vi[c] + BN_EPS);
        biasI[c] = bi[c] - mi[c] * s;
    } else if (i < 1344) {
        int c = i - 704;
        float s = ge[c] * rsqrtf(ve[c] + BN_EPS);
        biasE[c] = be[c] - me[c] * s;
    } else if (i < 1984) {
        int c = i - 1344;
        float s = go[c] * rsqrtf(vo[c] + BN_EPS);
        biasO[c] = bo[c] - mo[c] * s;
    }

    if (i >= 2048 && i < 7168) {         // wIt
        int u = i - 2048;
        int kc = u >> 8, w = u & 255;
        int mf = w >> 7, kh = (w >> 6) & 1, sl = w & 63;
        int oc = mf * 32 + (sl & 31);
        int k0 = kc * 32 + kh * 16 + (sl >> 5) * 8;
        float sc = gi[oc] * rsqrtf(vi[oc] + BN_EPS);
        unsigned d[4];
#pragma unroll
        for (int q = 0; q < 4; q++)
            d[q] = pack_bf16(w_in[oc * 640 + k0 + 2 * q] * sc,
                             w_in[oc * 640 + k0 + 2 * q + 1] * sc);
        ((uint4*)wIt)[u] = make_uint4(d[0], d[1], d[2], d[3]);
    }

    if (i >= 8192 && i < 59392) {        // wOt
        int u = i - 8192;
        int ci = u >> 9, w = u & 511;
        int mt = ci / 20, kc = ci - mt * 20;
        int mf = w >> 7, kh = (w >> 6) & 1, sl = w & 63;
        int oc = mt * 128 + mf * 32 + (sl & 31);
        int k0 = kc * 32 + kh * 16 + (sl >> 5) * 8;
        float sc = go[oc] * rsqrtf(vo[oc] + BN_EPS);
        unsigned d[4];
#pragma unroll
        for (int q = 0; q < 4; q++)
            d[q] = pack_bf16(w_out[oc * 640 + k0 + 2 * q] * sc,
                             w_out[oc * 640 + k0 + 2 * q + 1] * sc);
        ((uint4*)wOt)[u] = make_uint4(d[0], d[1], d[2], d[3]);
    }
}

// ===========================================================================
// feat B-unit generator: unit (kcAbs, t) of the B-frag tile, from slab/ctrs.
// ===========================================================================
__device__ __forceinline__ uint4 gen_feat_unit(const short* slab, const short* ctrs,
                                               int kcAbs, int t)
{
    const int hf = t >> 7, sl = t & 63;
    const int bkh = (t >> 6) & 1;
    const int cl = bkh * 16 + (sl >> 5) * 8;
    if (kcAbs < 2) {
        int spxC = (hf + 2) * 36 + (sl & 31) + 2;
        return *(const uint4*)&slab[spxC * 72 + kcAbs * 32 + cl];
    } else {
        int pxl = hf * 32 + (sl & 31);
        int idx = kcAbs - 2;
        int ksp = idx >> 1;
        int cb = (idx & 1) * 32 + cl;
        int kho = ksp / 5, kwo = ksp - kho * 5;
        int spx = (hf + kho) * 36 + (sl & 31) + kwo;
        const unsigned* nb = (const unsigned*)&slab[spx * 72 + cb];
        const unsigned* ct = (const unsigned*)&ctrs[pxl * 72 + cb];
        return make_uint4(pmul_fast(nb[0], ct[0]), pmul_fast(nb[1], ct[1]),
                          pmul_fast(nb[2], ct[2]), pmul_fast(nb[3], ct[3]));
    }
}

// ===========================================================================
// k_mega: identity + feat + emb + out, one block per 64-px tile, 640 thr.
// ===========================================================================
__global__ __launch_bounds__(640, 3)
void k_mega(const float* __restrict__ x,
            const float* __restrict__ s1, const float* __restrict__ b1c,
            const unsigned* __restrict__ wIt, const float* __restrict__ biasI,
            const unsigned* __restrict__ wEt, const float* __restrict__ biasE,
            const unsigned* __restrict__ wOt, const float* __restrict__ biasO,
            float* __restrict__ out)
{
    __shared__ short slab[216 * 72];     // 31104 B
    __shared__ short ctrs[64 * 72];      //  9216 B
    __shared__ float invDs[64];          //   256 B
    __shared__ char  stg[2][16384];      // 32768 B staging (4 kc x 256 uint4)
    __shared__ uint4 Ep[20 * 256];       // 81920 B: e in out-GEMM B-frag order

    const int tid = threadIdx.x;
    const int l = tid & 63;
    const int w = tid >> 6;              // wave 0..9, oc base = w*64
    const int mt = w >> 1, mf0 = (w & 1) * 2;
    const int pt = blockIdx.x;
    const int b = pt >> 4, r0 = (pt & 15) * 2;

    // ---- phase 0a: COMPUTE ident slab from x (fused identity GEMM) ----
    if (w < 7) {
        const int spx = w * 32 + (l & 31);
        const int spxc = spx < 216 ? spx : 215;
        const int sr = spxc / 36, sc = spxc - sr * 36;
        const int r = r0 + sr - 2, cc = sc - 2;
        const bool valid = (spx < 216) && (r >= 0) && (r < 32) && (cc >= 0) && (cc < 32);
        const int rcl = min(max(r, 0), 31), ccl = min(max(cc, 0), 31);
        const float* xp = x + (size_t)b * 655360 + (size_t)(rcl * 32 + ccl);
        const float vm = valid ? 1.f : 0.f;

        f32x16 accI[2];
#pragma unroll
        for (int i = 0; i < 2; i++)
#pragma unroll
            for (int rr = 0; rr < 16; rr++) accI[i][rr] = 0.f;

        for (int kc = 0; kc < 20; kc++) {
            uint4 av[2][2];
#pragma unroll
            for (int mi2 = 0; mi2 < 2; mi2++)
#pragma unroll
                for (int kh = 0; kh < 2; kh++)
                    av[mi2][kh] = ((const uint4*)wIt)[kc * 256 + (mi2 << 7) + (kh << 6) + l];
#pragma unroll
            for (int kh = 0; kh < 2; kh++) {
                const int ch0 = kc * 32 + kh * 16 + (l >> 5) * 8;
                float4 sA = *(const float4*)&s1[ch0], sB = *(const float4*)&s1[ch0 + 4];
                float4 bA = *(const float4*)&b1c[ch0], bB = *(const float4*)&b1c[ch0 + 4];
                const float* xc = xp + (size_t)ch0 * 1024;
                float vv[8];
                vv[0] = fmaxf(fmaf(xc[0],    sA.x, bA.x), 0.f) * vm;
                vv[1] = fmaxf(fmaf(xc[1024], sA.y, bA.y), 0.f) * vm;
                vv[2] = fmaxf(fmaf(xc[2048], sA.z, bA.z), 0.f) * vm;
                vv[3] = fmaxf(fmaf(xc[3072], sA.w, bA.w), 0.f) * vm;
                vv[4] = fmaxf(fmaf(xc[4096], sB.x, bB.x), 0.f) * vm;
                vv[5] = fmaxf(fmaf(xc[5120], sB.y, bB.y), 0.f) * vm;
                vv[6] = fmaxf(fmaf(xc[6144], sB.z, bB.z), 0.f) * vm;
                vv[7] = fmaxf(fmaf(xc[7168], sB.w, bB.w), 0.f) * vm;
                unsigned bu[4] = { pack_bf16(vv[0], vv[1]), pack_bf16(vv[2], vv[3]),
                                   pack_bf16(vv[4], vv[5]), pack_bf16(vv[6], vv[7]) };
                short8 bf = *(short8*)bu;
                accI[0] = __builtin_amdgcn_mfma_f32_32x32x16_bf16(*(short8*)&av[0][kh], bf, accI[0], 0, 0, 0);
                accI[1] = __builtin_amdgcn_mfma_f32_32x32x16_bf16(*(short8*)&av[1][kh], bf, accI[1], 0, 0, 0);
            }
        }
        // bias + relu (in place), pixel L2-norm across 64 oc
        float ss = 0.f;
#pragma unroll
        for (int mi2 = 0; mi2 < 2; mi2++)
#pragma unroll
            for (int rg = 0; rg < 4; rg++) {
                float4 bb = *(const float4*)&biasI[mi2 * 32 + 8 * rg + 4 * (l >> 5)];
#pragma unroll
                for (int q = 0; q < 4; q++) {
                    float bv = (q == 0) ? bb.x : (q == 1) ? bb.y : (q == 2) ? bb.z : bb.w;
                    float t = fmaxf(accI[mi2][rg * 4 + q] + bv, 0.f);
                    accI[mi2][rg * 4 + q] = t;
                    ss = fmaf(t, t, ss);
                }
            }
        ss += __shfl_xor(ss, 32);        // lanes l and l+32 hold the same px
        float inv = 1.f / fmaxf(sqrtf(ss), 1e-12f);
        if (spx < 216) {
#pragma unroll
            for (int mi2 = 0; mi2 < 2; mi2++)
#pragma unroll
                for (int rg = 0; rg < 4; rg++) {
                    unsigned d0 = pack_bf16(accI[mi2][rg * 4 + 0] * inv, accI[mi2][rg * 4 + 1] * inv);
                    unsigned d1 = pack_bf16(accI[mi2][rg * 4 + 2] * inv, accI[mi2][rg * 4 + 3] * inv);
                    if (!valid) { d0 = 0u; d1 = 0u; }
                    *(uint2*)&slab[spx * 72 + mi2 * 32 + 8 * rg + 4 * (l >> 5)] = make_uint2(d0, d1);
                }
        }
    }
    __syncthreads();

    // ---- phase 0b: invD (featureL2Norm of corr) ----
    if (tid < 512) {
        int px = tid >> 3, part = tid & 7;
        int rh = px >> 5, rw = px & 31;
        float ctr[8];
        const unsigned* cp = (const unsigned*)&slab[((rh + 2) * 36 + rw + 2) * 72 + part * 8];
#pragma unroll
        for (int d = 0; d < 4; d++) { ctr[2 * d] = bflo(cp[d]); ctr[2 * d + 1] = bfhi(cp[d]); }
        float sum = 0.f;
#pragma unroll
        for (int k = 0; k < 25; k++) {
            const int kh = k / 5, kw = k % 5;
            const unsigned* nb = (const unsigned*)&slab[((rh + kh) * 36 + rw + kw) * 72 + part * 8];
#pragma unroll
            for (int d = 0; d < 4; d++) {
                float q0 = bflo(nb[d]) * ctr[2 * d];
                float q1 = bfhi(nb[d]) * ctr[2 * d + 1];
                sum = fmaf(q0, q0, sum); sum = fmaf(q1, q1, sum);
            }
        }
        sum += __shfl_xor(sum, 1);
        sum += __shfl_xor(sum, 2);
        sum += __shfl_xor(sum, 4);
        if (part == 0) invDs[px] = rsqrtf(sum + 1e-6f);
    }
    __syncthreads();

    // ---- phase 0c: normalized centers ----
    if (tid < 512) {
        int px = tid >> 3, q = tid & 7;
        int spx = ((px >> 5) + 2) * 36 + (px & 31) + 2;
        const unsigned* src = (const unsigned*)&slab[spx * 72 + q * 8];
        float iv = invDs[px];
        unsigned d[4];
#pragma unroll
        for (int dd = 0; dd < 4; dd++)
            d[dd] = pk_hu(bflo(src[dd]) * iv, bfhi(src[dd]) * iv);
        *(uint4*)&ctrs[px * 72 + q * 8] = make_uint4(d[0], d[1], d[2], d[3]);
    }
    __syncthreads();

    // ---- phase 1: emb GEMM with on-the-fly B-chunk generation ----
    const uint4* A = (const uint4*)wEt + (size_t)(mt * 52) * 512;
    const bool has2 = (tid < 384);

    f32x16 acc[2][2];
#pragma unroll
    for (int i = 0; i < 2; i++)
#pragma unroll
        for (int j = 0; j < 2; j++)
#pragma unroll
            for (int r = 0; r < 16; r++) acc[i][j][r] = 0.f;

    {
        uint4 f = gen_feat_unit(slab, ctrs, (tid >> 8), tid & 255);
        *(uint4*)&stg[0][tid * 16] = f;
        if (has2) {
            int u = tid + 640;
            uint4 f2 = gen_feat_unit(slab, ctrs, (u >> 8), u & 255);
            *(uint4*)&stg[0][u * 16] = f2;
        }
    }
    __syncthreads();

    for (int c = 0; c < 13; c++) {
        const int cur = c & 1, nxt = cur ^ 1;
        if (c < 12) {                    // generate next chunk while others MFMA
            int kc0 = (c + 1) * 4;
            uint4 f = gen_feat_unit(slab, ctrs, kc0 + (tid >> 8), tid & 255);
            *(uint4*)&stg[nxt][tid * 16] = f;
            if (has2) {
                int u = tid + 640;
                uint4 f2 = gen_feat_unit(slab, ctrs, kc0 + (u >> 8), u & 255);
                *(uint4*)&stg[nxt][u * 16] = f2;
            }
        }
#pragma unroll
        for (int kcL = 0; kcL < 4; kcL++) {
            const int kc = c * 4 + kcL;
            uint4 av[2][2], bv[2][2];
#pragma unroll
            for (int mi = 0; mi < 2; mi++)
#pragma unroll
                for (int kh = 0; kh < 2; kh++)
                    av[mi][kh] = A[(size_t)kc * 512 + (((mf0 + mi) * 2 + kh) << 6) + l];
#pragma unroll
            for (int ni = 0; ni < 2; ni++)
#pragma unroll
                for (int kh = 0; kh < 2; kh++)
                    bv[ni][kh] = *(const uint4*)&stg[cur][(kcL * 256 + (ni << 7) + (kh << 6) + l) * 16];
#pragma unroll
            for (int kh = 0; kh < 2; kh++) {
                acc[0][0] = __builtin_amdgcn_mfma_f32_32x32x16_bf16(*(short8*)&av[0][kh], *(short8*)&bv[0][kh], acc[0][0], 0, 0, 0);
                acc[0][1] = __builtin_amdgcn_mfma_f32_32x32x16_bf16(*(short8*)&av[0][kh], *(short8*)&bv[1][kh], acc[0][1], 0, 0, 0);
                acc[1][0] = __builtin_amdgcn_mfma_f32_32x32x16_bf16(*(short8*)&av[1][kh], *(short8*)&bv[0][kh], acc[1][0], 0, 0, 0);
                acc[1][1] = __builtin_amdgcn_mfma_f32_32x32x16_bf16(*(short8*)&av[1][kh], *(short8*)&bv[1][kh], acc[1][1], 0, 0, 0);
            }
        }
        __syncthreads();
    }

    // ---- phase 2: bias+relu epilogue into Ep (out-GEMM B-frag order) ----
#pragma unroll
    for (int mi = 0; mi < 2; mi++) {
        const int kbase = (w * 2 + mi) * 256;
#pragma unroll
        for (int ni = 0; ni < 2; ni++) {
#pragma unroll
            for (int rg = 0; rg < 4; rg++) {
                int ocb = w * 64 + mi * 32 + 8 * rg + 4 * (l >> 5);
                float4 bb = *(const float4*)&biasE[ocb];
                unsigned d0 = pack_bf16(fmaxf(acc[mi][ni][rg * 4 + 0] + bb.x, 0.f),
                                        fmaxf(acc[mi][ni][rg * 4 + 1] + bb.y, 0.f));
                unsigned d1 = pack_bf16(fmaxf(acc[mi][ni][rg * 4 + 2] + bb.z, 0.f),
                                        fmaxf(acc[mi][ni][rg * 4 + 3] + bb.w, 0.f));
                int unit = kbase + (ni << 7) + ((rg >> 1) << 6) + ((rg & 1) << 5) + (l & 31);
                ((uint2*)Ep)[unit * 2 + (l >> 5)] = make_uint2(d0, d1);
            }
        }
    }
    __syncthreads();

    // ---- phase 3: out GEMM. B = Ep (LDS), A = wOt (L2). ----
    const int p0 = pt * 64;
    const int hw0 = p0 & 1023;
    const uint4* Ao = (const uint4*)wOt + (size_t)(mt * 20) * 512;

    f32x16 acc2[2][2];
#pragma unroll
    for (int i = 0; i < 2; i++)
#pragma unroll
        for (int j = 0; j < 2; j++)
#pragma unroll
            for (int r = 0; r < 16; r++) acc2[i][j][r] = 0.f;

#pragma unroll 2
    for (int kc = 0; kc < 20; kc++) {
        uint4 av[2][2], bv[2][2];
#pragma unroll
        for (int mi = 0; mi < 2; mi++)
#pragma unroll
            for (int kh = 0; kh < 2; kh++)
                av[mi][kh] = Ao[(size_t)kc * 512 + (((mf0 + mi) * 2 + kh) << 6) + l];
#pragma unroll
        for (int ni = 0; ni < 2; ni++)
#pragma unroll
            for (int kh = 0; kh < 2; kh++)
                bv[ni][kh] = Ep[kc * 256 + (ni << 7) + (kh << 6) + l];
#pragma unroll
        for (int kh = 0; kh < 2; kh++) {
            acc2[0][0] = __builtin_amdgcn_mfma_f32_32x32x16_bf16(*(short8*)&av[0][kh], *(short8*)&bv[0][kh], acc2[0][0], 0, 0, 0);
            acc2[0][1] = __builtin_amdgcn_mfma_f32_32x32x16_bf16(*(short8*)&av[0][kh], *(short8*)&bv[1][kh], acc2[0][1], 0, 0, 0);
            acc2[1][0] = __builtin_amdgcn_mfma_f32_32x32x16_bf16(*(short8*)&av[1][kh], *(short8*)&bv[0][kh], acc2[1][0], 0, 0, 0);
            acc2[1][1] = __builtin_amdgcn_mfma_f32_32x32x16_bf16(*(short8*)&av[1][kh], *(short8*)&bv[1][kh], acc2[1][1], 0, 0, 0);
        }
    }

#pragma unroll
    for (int mi = 0; mi < 2; mi++)
#pragma unroll
        for (int ni = 0; ni < 2; ni++) {
            int pxl = ni * 32 + (l & 31);
#pragma unroll
            for (int r = 0; r < 16; r++) {
                int oc = w * 64 + mi * 32 + (r & 3) + 8 * (r >> 2) + 4 * (l >> 5);
                out[((size_t)b * 640 + oc) * 1024 + hw0 + pxl] = acc2[mi][ni][r] + biasO[oc];
            }
        }
}

// ===========================================================================
extern "C" void kernel_launch(void* const* d_in, const int* in_sizes, int n_in,
                              void* d_out, int out_size, void* d_ws, size_t ws_size,
                              hipStream_t stream)
{
    const float* x    = (const float*)d_in[0];
    const float* g1   = (const float*)d_in[1];
    const float* b1   = (const float*)d_in[2];
    const float* m1   = (const float*)d_in[3];
    const float* v1   = (const float*)d_in[4];
    const float* w_in = (const float*)d_in[5];
    const float* gi   = (const float*)d_in[6];
    const float* bi   = (const float*)d_in[7];
    const float* mi   = (const float*)d_in[8];
    const float* vi   = (const float*)d_in[9];
    const float* w_emb= (const float*)d_in[10];
    const float* ge   = (const float*)d_in[11];
    const float* be   = (const float*)d_in[12];
    const float* me   = (const float*)d_in[13];
    const float* ve   = (const float*)d_in[14];
    const float* w_out= (const float*)d_in[15];
    const float* go   = (const float*)d_in[16];
    const float* bo   = (const float*)d_in[17];
    const float* mo   = (const float*)d_in[18];
    const float* vo   = (const float*)d_in[19];

    char* ws = (char*)d_ws;
    float*    s1    = (float*)(ws + 0);
    float*    b1c   = (float*)(ws + 2560);
    float*    biasI = (float*)(ws + 5120);
    float*    biasE = (float*)(ws + 5376);
    float*    biasO = (float*)(ws + 7936);
    unsigned* wIt   = (unsigned*)(ws + 16384);
    unsigned* wOt   = (unsigned*)(ws + 98304);
    unsigned* wEt   = (unsigned*)(ws + 917504);   // ends 3,047,424
    float*    out   = (float*)d_out;

    k_prepAll<<<872, 256, 0, stream>>>(g1, b1, m1, v1, w_in, gi, bi, mi, vi,
                                       w_emb, ge, be, me, ve, w_out, go, bo, mo, vo,
                                       s1, b1c, biasI, biasE, biasO, wIt, wEt, wOt);
    k_mega<<<256, 640, 0, stream>>>(x, s1, b1c, wIt, biasI,
                                    wEt, biasE, wOt, biasO, out);
}

// Round 8
// 193.962 us; speedup vs baseline: 1.1435x; 1.0117x over previous
//
#include <hip/hip_runtime.h>
#include <math.h>

#define BN_EPS 1e-5f

using short8  = __attribute__((ext_vector_type(8))) short;
using f32x16  = __attribute__((ext_vector_type(16))) float;

// ---------------------------------------------------------------------------
// x (16,640,32,32) fp32. Pixels P=16384, p = b*1024 + h*32 + w.
// feat K-order (permuted): kg'<64 -> identity ch kg'; kg'>=64: t=kg'-64,
//   ksp=t>>6 (spatial 0..24), c=t&63; orig w_emb col = 64 + c*25 + ksp.
// Weight tiles (A-frag order), per kc (K=32 chunk): see k_prepAll.
//
// k_mega v2 (identity+feat+emb+out), one block per 64-px tile, 640 thr =
// 10 waves, wave w owns oc [64w,64w+64).
// Schedule changes vs v1 (all register-double-buffer / barrier reduction;
// dataflow identical):
//  - phase 0a: x-loads (16/kc) and wIt A-frags prefetched one kc ahead;
//    s1/b1c staged to LDS once; OOB handled at store (no vm multiply).
//  - phase 1: 8-kc chunks (7 barriers vs 13), rolling prefetch of next-kc
//    A (L2) and B (LDS).
//  - phase 3: rolling prefetch of A and Ep fragments.
//  - LDS aliased: {slab+s1/b1c|ctrs+invD+stg dbuf} (106112 B) reused as
//    Ep (81920 B) after the last phase-1 barrier. Peak 106112 B.
// ---------------------------------------------------------------------------

__device__ __forceinline__ float bflo(unsigned u) { return __uint_as_float(u << 16); }
__device__ __forceinline__ float bfhi(unsigned u) { return __uint_as_float(u & 0xffff0000u); }

__device__ __forceinline__ unsigned bf16_rne(float f) {
    unsigned u = __float_as_uint(f);
    return (u + 0x7fffu + ((u >> 16) & 1u)) >> 16;
}
__device__ __forceinline__ unsigned pack_bf16(float lo, float hi) {
    return bf16_rne(lo) | (bf16_rne(hi) << 16);
}
__device__ __forceinline__ unsigned pk_hu(float lo, float hi) {
    unsigned a = __float_as_uint(lo) + 0x8000u;
    unsigned b = __float_as_uint(hi) + 0x8000u;
    return __builtin_amdgcn_perm(b, a, 0x07060302u);
}
__device__ __forceinline__ unsigned pmul_fast(unsigned a, unsigned b) {
    return pk_hu(bflo(a) * bflo(b), bfhi(a) * bfhi(b));
}

// ===========================================================================
// k_prepAll: blocks [0,640) build wEt (per-oc row staging);
//            blocks [640,872) do scalars + wIt + wOt.
// ===========================================================================
__global__ __launch_bounds__(256)
void k_prepAll(const float* __restrict__ g1, const float* __restrict__ b1,
               const float* __restrict__ m1, const float* __restrict__ v1,
               const float* __restrict__ w_in,
               const float* __restrict__ gi, const float* __restrict__ bi,
               const float* __restrict__ mi, const float* __restrict__ vi,
               const float* __restrict__ w_emb,
               const float* __restrict__ ge, const float* __restrict__ be,
               const float* __restrict__ me, const float* __restrict__ ve,
               const float* __restrict__ w_out,
               const float* __restrict__ go, const float* __restrict__ bo,
               const float* __restrict__ mo, const float* __restrict__ vo,
               float* __restrict__ s1, float* __restrict__ b1c,
               float* __restrict__ biasI, float* __restrict__ biasE, float* __restrict__ biasO,
               unsigned* __restrict__ wIt, unsigned* __restrict__ wEt, unsigned* __restrict__ wOt)
{
    __shared__ float row[1664];
    const int tid = threadIdx.x;

    if (blockIdx.x < 640) {
        const int oc = blockIdx.x;
#pragma unroll
        for (int it = 0; it < 2; it++) {
            int u = it * 256 + tid;
            if (u < 416)
                ((float4*)row)[u] = ((const float4*)&w_emb[(size_t)oc * 1664])[u];
        }
        __syncthreads();
        if (tid < 208) {
            int kc = tid >> 2, kh = (tid >> 1) & 1, ksub = tid & 1;
            int k0 = kc * 32 + kh * 16 + ksub * 8;
            float sc = ge[oc] * rsqrtf(ve[oc] + BN_EPS);
            float v[8];
#pragma unroll
            for (int j = 0; j < 8; j++) {
                int kgp = k0 + j;
                int orig;
                if (kgp < 64) orig = kgp;
                else { int t = kgp - 64; orig = 64 + (t & 63) * 25 + (t >> 6); }
                v[j] = row[orig] * sc;
            }
            int mt = oc >> 7, mf = (oc >> 5) & 3;
            int idx = (mt * 52 + kc) * 512 + (mf * 2 + kh) * 64 + ksub * 32 + (oc & 31);
            ((uint4*)wEt)[idx] = make_uint4(pack_bf16(v[0], v[1]), pack_bf16(v[2], v[3]),
                                            pack_bf16(v[4], v[5]), pack_bf16(v[6], v[7]));
        }
        return;
    }

    int i = (blockIdx.x - 640) * 256 + tid;

    if (i < 640) {
        float s = g1[i] * rsqrtf(v1[i] + BN_EPS);
        s1[i] = s; b1c[i] = b1[i] - m1[i] * s;
    } else if (i < 704) {
        int c = i - 640;
        float s = gi[c] * rsqrtf(vi[c] + BN_EPS);
        biasI[c] = bi[c] - mi[c] * s;
    } else if (i < 1344) {
        int c = i - 704;
        float s = ge[c] * rsqrtf(ve[c] + BN_EPS);
        biasE[c] = be[c] - me[c] * s;
    } else if (i < 1984) {
        int c = i - 1344;
        float s = go[c] * rsqrtf(vo[c] + BN_EPS);
        biasO[c] = bo[c] - mo[c] * s;
    }

    if (i >= 2048 && i < 7168) {         // wIt
        int u = i - 2048;
        int kc = u >> 8, w = u & 255;
        int mf = w >> 7, kh = (w >> 6) & 1, sl = w & 63;
        int oc = mf * 32 + (sl & 31);
        int k0 = kc * 32 + kh * 16 + (sl >> 5) * 8;
        float sc = gi[oc] * rsqrtf(vi[oc] + BN_EPS);
        unsigned d[4];
#pragma unroll
        for (int q = 0; q < 4; q++)
            d[q] = pack_bf16(w_in[oc * 640 + k0 + 2 * q] * sc,
                             w_in[oc * 640 + k0 + 2 * q + 1] * sc);
        ((uint4*)wIt)[u] = make_uint4(d[0], d[1], d[2], d[3]);
    }

    if (i >= 8192 && i < 59392) {        // wOt
        int u = i - 8192;
        int ci = u >> 9, w = u & 511;
        int mt = ci / 20, kc = ci - mt * 20;
        int mf = w >> 7, kh = (w >> 6) & 1, sl = w & 63;
        int oc = mt * 128 + mf * 32 + (sl & 31);
        int k0 = kc * 32 + kh * 16 + (sl >> 5) * 8;
        float sc = go[oc] * rsqrtf(vo[oc] + BN_EPS);
        unsigned d[4];
#pragma unroll
        for (int q = 0; q < 4; q++)
            d[q] = pack_bf16(w_out[oc * 640 + k0 + 2 * q] * sc,
                             w_out[oc * 640 + k0 + 2 * q + 1] * sc);
        ((uint4*)wOt)[u] = make_uint4(d[0], d[1], d[2], d[3]);
    }
}

// ===========================================================================
// feat B-unit generator: unit (kcAbs, t) of the B-frag tile, from slab/ctrs.
// ===========================================================================
__device__ __forceinline__ uint4 gen_feat_unit(const short* slab, const short* ctrs,
                                               int kcAbs, int t)
{
    const int hf = t >> 7, sl = t & 63;
    const int bkh = (t >> 6) & 1;
    const int cl = bkh * 16 + (sl >> 5) * 8;
    if (kcAbs < 2) {
        int spxC = (hf + 2) * 36 + (sl & 31) + 2;
        return *(const uint4*)&slab[spxC * 72 + kcAbs * 32 + cl];
    } else {
        int pxl = hf * 32 + (sl & 31);
        int idx = kcAbs - 2;
        int ksp = idx >> 1;
        int cb = (idx & 1) * 32 + cl;
        int kho = ksp / 5, kwo = ksp - kho * 5;
        int spx = (hf + kho) * 36 + (sl & 31) + kwo;
        const unsigned* nb = (const unsigned*)&slab[spx * 72 + cb];
        const unsigned* ct = (const unsigned*)&ctrs[pxl * 72 + cb];
        return make_uint4(pmul_fast(nb[0], ct[0]), pmul_fast(nb[1], ct[1]),
                          pmul_fast(nb[2], ct[2]), pmul_fast(nb[3], ct[3]));
    }
}

// ===========================================================================
// k_mega v2: identity + feat + emb + out, one block per 64-px tile, 640 thr.
// LDS layout (106112 B total, aliased):
//   [0      , 31104) slab  (216 x 72 shorts)          -- phases 0a..1
//   [31104  , 36224) s1L/b1L staging (2 x 2560 B)     -- phase 0a only
//   [31104  , 40320) ctrs  (64 x 72 shorts)           -- phases 0c..1
//   [40320  , 40576) invD                              -- phase 0b..0c
//   [40576  , 106112) stg dbuf (2 x 32768 = 8 kc each) -- phase 1
//   [0      ,  81920) Ep (20 kc x 256 uint4)           -- phases 2..3
// ===========================================================================
__global__ __launch_bounds__(640, 3)
void k_mega(const float* __restrict__ x,
            const float* __restrict__ s1, const float* __restrict__ b1c,
            const unsigned* __restrict__ wIt, const float* __restrict__ biasI,
            const unsigned* __restrict__ wEt, const float* __restrict__ biasE,
            const unsigned* __restrict__ wOt, const float* __restrict__ biasO,
            float* __restrict__ out)
{
    __shared__ __align__(16) char Lds[106112];
    short* slab  = (short*)Lds;
    float* s1L   = (float*)(Lds + 31104);
    float* b1L   = (float*)(Lds + 31104 + 2560);
    short* ctrs  = (short*)(Lds + 31104);
    float* invDs = (float*)(Lds + 40320);
    char*  stg   = Lds + 40576;
    uint4* Ep    = (uint4*)Lds;

    const int tid = threadIdx.x;
    const int l = tid & 63;
    const int w = tid >> 6;              // wave 0..9, oc base = w*64
    const int mt = w >> 1, mf0 = (w & 1) * 2;
    const int pt = blockIdx.x;
    const int b = pt >> 4, r0 = (pt & 15) * 2;

    // ---- stage s1/b1c to LDS (640 floats each) ----
    if (tid < 160)       ((float4*)s1L)[tid]       = ((const float4*)s1)[tid];
    else if (tid < 320)  ((float4*)b1L)[tid - 160] = ((const float4*)b1c)[tid - 160];
    __syncthreads();

    // ---- phase 0a: COMPUTE ident slab from x (fused identity GEMM) ----
    if (w < 7) {
        const int spx = w * 32 + (l & 31);
        const int spxc = spx < 216 ? spx : 215;
        const int sr = spxc / 36, sc = spxc - sr * 36;
        const int r = r0 + sr - 2, cc = sc - 2;
        const bool valid = (spx < 216) && (r >= 0) && (r < 32) && (cc >= 0) && (cc < 32);
        const int rcl = min(max(r, 0), 31), ccl = min(max(cc, 0), 31);
        const float* xp = x + (size_t)b * 655360 + (size_t)(rcl * 32 + ccl);
        const int co = (l >> 5) * 8;

        f32x16 accI[2];
#pragma unroll
        for (int i = 0; i < 2; i++)
#pragma unroll
            for (int rr = 0; rr < 16; rr++) accI[i][rr] = 0.f;

        float xv[16], xn[16];
        uint4 av[2][2], avn[2][2];
        // preload kc 0
#pragma unroll
        for (int kh = 0; kh < 2; kh++)
#pragma unroll
            for (int j = 0; j < 8; j++)
                xv[kh * 8 + j] = xp[(size_t)(kh * 16 + co + j) * 1024];
#pragma unroll
        for (int mi2 = 0; mi2 < 2; mi2++)
#pragma unroll
            for (int kh = 0; kh < 2; kh++)
                av[mi2][kh] = ((const uint4*)wIt)[(mi2 << 7) + (kh << 6) + l];

        for (int kc = 0; kc < 20; kc++) {
            if (kc < 19) {               // prefetch next kc (x from HBM/L3, A from L2)
#pragma unroll
                for (int kh = 0; kh < 2; kh++)
#pragma unroll
                    for (int j = 0; j < 8; j++)
                        xn[kh * 8 + j] = xp[(size_t)((kc + 1) * 32 + kh * 16 + co + j) * 1024];
#pragma unroll
                for (int mi2 = 0; mi2 < 2; mi2++)
#pragma unroll
                    for (int kh = 0; kh < 2; kh++)
                        avn[mi2][kh] = ((const uint4*)wIt)[(kc + 1) * 256 + (mi2 << 7) + (kh << 6) + l];
            }
#pragma unroll
            for (int kh = 0; kh < 2; kh++) {
                const int ch0 = kc * 32 + kh * 16 + co;
                float4 sA = *(const float4*)&s1L[ch0], sB = *(const float4*)&s1L[ch0 + 4];
                float4 bA = *(const float4*)&b1L[ch0], bB = *(const float4*)&b1L[ch0 + 4];
                float vv[8];
                vv[0] = fmaxf(fmaf(xv[kh * 8 + 0], sA.x, bA.x), 0.f);
                vv[1] = fmaxf(fmaf(xv[kh * 8 + 1], sA.y, bA.y), 0.f);
                vv[2] = fmaxf(fmaf(xv[kh * 8 + 2], sA.z, bA.z), 0.f);
                vv[3] = fmaxf(fmaf(xv[kh * 8 + 3], sA.w, bA.w), 0.f);
                vv[4] = fmaxf(fmaf(xv[kh * 8 + 4], sB.x, bB.x), 0.f);
                vv[5] = fmaxf(fmaf(xv[kh * 8 + 5], sB.y, bB.y), 0.f);
                vv[6] = fmaxf(fmaf(xv[kh * 8 + 6], sB.z, bB.z), 0.f);
                vv[7] = fmaxf(fmaf(xv[kh * 8 + 7], sB.w, bB.w), 0.f);
                unsigned bu[4] = { pack_bf16(vv[0], vv[1]), pack_bf16(vv[2], vv[3]),
                                   pack_bf16(vv[4], vv[5]), pack_bf16(vv[6], vv[7]) };
                short8 bf = *(short8*)bu;
                accI[0] = __builtin_amdgcn_mfma_f32_32x32x16_bf16(*(short8*)&av[0][kh], bf, accI[0], 0, 0, 0);
                accI[1] = __builtin_amdgcn_mfma_f32_32x32x16_bf16(*(short8*)&av[1][kh], bf, accI[1], 0, 0, 0);
            }
            if (kc < 19) {
#pragma unroll
                for (int q = 0; q < 16; q++) xv[q] = xn[q];
#pragma unroll
                for (int mi2 = 0; mi2 < 2; mi2++)
#pragma unroll
                    for (int kh = 0; kh < 2; kh++) av[mi2][kh] = avn[mi2][kh];
            }
        }
        // bias + relu (in place), pixel L2-norm across 64 oc
        float ss = 0.f;
#pragma unroll
        for (int mi2 = 0; mi2 < 2; mi2++)
#pragma unroll
            for (int rg = 0; rg < 4; rg++) {
                float4 bb = *(const float4*)&biasI[mi2 * 32 + 8 * rg + 4 * (l >> 5)];
#pragma unroll
                for (int q = 0; q < 4; q++) {
                    float bv = (q == 0) ? bb.x : (q == 1) ? bb.y : (q == 2) ? bb.z : bb.w;
                    float t = fmaxf(accI[mi2][rg * 4 + q] + bv, 0.f);
                    accI[mi2][rg * 4 + q] = t;
                    ss = fmaf(t, t, ss);
                }
            }
        ss += __shfl_xor(ss, 32);        // lanes l and l+32 hold the same px
        float inv = 1.f / fmaxf(sqrtf(ss), 1e-12f);
        if (spx < 216) {
#pragma unroll
            for (int mi2 = 0; mi2 < 2; mi2++)
#pragma unroll
                for (int rg = 0; rg < 4; rg++) {
                    unsigned d0 = pack_bf16(accI[mi2][rg * 4 + 0] * inv, accI[mi2][rg * 4 + 1] * inv);
                    unsigned d1 = pack_bf16(accI[mi2][rg * 4 + 2] * inv, accI[mi2][rg * 4 + 3] * inv);
                    if (!valid) { d0 = 0u; d1 = 0u; }
                    *(uint2*)&slab[spx * 72 + mi2 * 32 + 8 * rg + 4 * (l >> 5)] = make_uint2(d0, d1);
                }
        }
    }
    __syncthreads();

    // ---- phase 0b: invD (featureL2Norm of corr) ----
    if (tid < 512) {
        int px = tid >> 3, part = tid & 7;
        int rh = px >> 5, rw = px & 31;
        float ctr[8];
        const unsigned* cp = (const unsigned*)&slab[((rh + 2) * 36 + rw + 2) * 72 + part * 8];
#pragma unroll
        for (int d = 0; d < 4; d++) { ctr[2 * d] = bflo(cp[d]); ctr[2 * d + 1] = bfhi(cp[d]); }
        float sum = 0.f;
#pragma unroll
        for (int k = 0; k < 25; k++) {
            const int kh = k / 5, kw = k % 5;
            const unsigned* nb = (const unsigned*)&slab[((rh + kh) * 36 + rw + kw) * 72 + part * 8];
#pragma unroll
            for (int d = 0; d < 4; d++) {
                float q0 = bflo(nb[d]) * ctr[2 * d];
                float q1 = bfhi(nb[d]) * ctr[2 * d + 1];
                sum = fmaf(q0, q0, sum); sum = fmaf(q1, q1, sum);
            }
        }
        sum += __shfl_xor(sum, 1);
        sum += __shfl_xor(sum, 2);
        sum += __shfl_xor(sum, 4);
        if (part == 0) invDs[px] = rsqrtf(sum + 1e-6f);
    }
    __syncthreads();

    // ---- phase 0c: normalized centers ----
    if (tid < 512) {
        int px = tid >> 3, q = tid & 7;
        int spx = ((px >> 5) + 2) * 36 + (px & 31) + 2;
        const unsigned* src = (const unsigned*)&slab[spx * 72 + q * 8];
        float iv = invDs[px];
        unsigned d[4];
#pragma unroll
        for (int dd = 0; dd < 4; dd++)
            d[dd] = pk_hu(bflo(src[dd]) * iv, bfhi(src[dd]) * iv);
        *(uint4*)&ctrs[px * 72 + q * 8] = make_uint4(d[0], d[1], d[2], d[3]);
    }
    __syncthreads();

    // ---- phase 1: emb GEMM, 8-kc chunks, rolling A/B prefetch ----
    const uint4* A = (const uint4*)wEt + (size_t)(mt * 52) * 512;

    f32x16 acc[2][2];
#pragma unroll
    for (int i = 0; i < 2; i++)
#pragma unroll
        for (int j = 0; j < 2; j++)
#pragma unroll
            for (int r = 0; r < 16; r++) acc[i][j][r] = 0.f;

    uint4 avc[2][2];
#pragma unroll
    for (int mi = 0; mi < 2; mi++)
#pragma unroll
        for (int kh = 0; kh < 2; kh++)
            avc[mi][kh] = A[(((mf0 + mi) * 2 + kh) << 6) + l];

    // gen chunk 0 (kc 0..7)
#pragma unroll
    for (int k = 0; k < 4; k++) {
        int u = tid + k * 640;
        if (u < 2048) {
            uint4 f = gen_feat_unit(slab, ctrs, (u >> 8), u & 255);
            *(uint4*)&stg[u * 16] = f;
        }
    }
    __syncthreads();

    uint4 bvc[2][2];
#pragma unroll
    for (int ni = 0; ni < 2; ni++)
#pragma unroll
        for (int kh = 0; kh < 2; kh++)
            bvc[ni][kh] = *(const uint4*)&stg[((ni << 7) + (kh << 6) + l) * 16];

#pragma unroll 1
    for (int c = 0; c < 6; c++) {
        const int cur = c & 1, nxt = cur ^ 1;
        const int base = c * 8;
        // generate next chunk into the free buffer (chunk c+1: 8 kc, last is 4)
        {
            const int nunits = (c < 5) ? 2048 : 1024;
            const int nbase = base + 8;
#pragma unroll
            for (int k = 0; k < 4; k++) {
                int u = tid + k * 640;
                if (u < nunits) {
                    uint4 f = gen_feat_unit(slab, ctrs, nbase + (u >> 8), u & 255);
                    *(uint4*)&stg[nxt * 32768 + u * 16] = f;
                }
            }
        }
#pragma unroll
        for (int kcL = 0; kcL < 8; kcL++) {
            const int kc = base + kcL;
            uint4 avn[2][2];
#pragma unroll
            for (int mi = 0; mi < 2; mi++)
#pragma unroll
                for (int kh = 0; kh < 2; kh++)
                    avn[mi][kh] = A[(size_t)(kc + 1) * 512 + (((mf0 + mi) * 2 + kh) << 6) + l];
            uint4 bvn[2][2];
            if (kcL < 7) {
#pragma unroll
                for (int ni = 0; ni < 2; ni++)
#pragma unroll
                    for (int kh = 0; kh < 2; kh++)
                        bvn[ni][kh] = *(const uint4*)&stg[cur * 32768 + ((kcL + 1) * 256 + (ni << 7) + (kh << 6) + l) * 16];
            }
#pragma unroll
            for (int kh = 0; kh < 2; kh++) {
                acc[0][0] = __builtin_amdgcn_mfma_f32_32x32x16_bf16(*(short8*)&avc[0][kh], *(short8*)&bvc[0][kh], acc[0][0], 0, 0, 0);
                acc[0][1] = __builtin_amdgcn_mfma_f32_32x32x16_bf16(*(short8*)&avc[0][kh], *(short8*)&bvc[1][kh], acc[0][1], 0, 0, 0);
                acc[1][0] = __builtin_amdgcn_mfma_f32_32x32x16_bf16(*(short8*)&avc[1][kh], *(short8*)&bvc[0][kh], acc[1][0], 0, 0, 0);
                acc[1][1] = __builtin_amdgcn_mfma_f32_32x32x16_bf16(*(short8*)&avc[1][kh], *(short8*)&bvc[1][kh], acc[1][1], 0, 0, 0);
            }
#pragma unroll
            for (int mi = 0; mi < 2; mi++)
#pragma unroll
                for (int kh = 0; kh < 2; kh++) avc[mi][kh] = avn[mi][kh];
            if (kcL < 7) {
#pragma unroll
                for (int ni = 0; ni < 2; ni++)
#pragma unroll
                    for (int kh = 0; kh < 2; kh++) bvc[ni][kh] = bvn[ni][kh];
            }
        }
        __syncthreads();
        // load first bv of next chunk from the buffer just generated
#pragma unroll
        for (int ni = 0; ni < 2; ni++)
#pragma unroll
            for (int kh = 0; kh < 2; kh++)
                bvc[ni][kh] = *(const uint4*)&stg[nxt * 32768 + ((ni << 7) + (kh << 6) + l) * 16];
    }
    // final chunk: kc 48..51, buffer index 6&1 = 0
#pragma unroll
    for (int kcL = 0; kcL < 4; kcL++) {
        const int kc = 48 + kcL;
        uint4 avn[2][2], bvn[2][2];
        if (kcL < 3) {
#pragma unroll
            for (int mi = 0; mi < 2; mi++)
#pragma unroll
                for (int kh = 0; kh < 2; kh++)
                    avn[mi][kh] = A[(size_t)(kc + 1) * 512 + (((mf0 + mi) * 2 + kh) << 6) + l];
#pragma unroll
            for (int ni = 0; ni < 2; ni++)
#pragma unroll
                for (int kh = 0; kh < 2; kh++)
                    bvn[ni][kh] = *(const uint4*)&stg[((kcL + 1) * 256 + (ni << 7) + (kh << 6) + l) * 16];
        }
#pragma unroll
        for (int kh = 0; kh < 2; kh++) {
            acc[0][0] = __builtin_amdgcn_mfma_f32_32x32x16_bf16(*(short8*)&avc[0][kh], *(short8*)&bvc[0][kh], acc[0][0], 0, 0, 0);
            acc[0][1] = __builtin_amdgcn_mfma_f32_32x32x16_bf16(*(short8*)&avc[0][kh], *(short8*)&bvc[1][kh], acc[0][1], 0, 0, 0);
            acc[1][0] = __builtin_amdgcn_mfma_f32_32x32x16_bf16(*(short8*)&avc[1][kh], *(short8*)&bvc[0][kh], acc[1][0], 0, 0, 0);
            acc[1][1] = __builtin_amdgcn_mfma_f32_32x32x16_bf16(*(short8*)&avc[1][kh], *(short8*)&bvc[1][kh], acc[1][1], 0, 0, 0);
        }
        if (kcL < 3) {
#pragma unroll
            for (int mi = 0; mi < 2; mi++)
#pragma unroll
                for (int kh = 0; kh < 2; kh++) avc[mi][kh] = avn[mi][kh];
#pragma unroll
            for (int ni = 0; ni < 2; ni++)
#pragma unroll
                for (int kh = 0; kh < 2; kh++) bvc[ni][kh] = bvn[ni][kh];
        }
    }
    __syncthreads();                     // all phase-1 LDS reads done: Ep may alias

    // ---- phase 2: bias+relu epilogue into Ep (out-GEMM B-frag order) ----
#pragma unroll
    for (int mi = 0; mi < 2; mi++) {
        const int kbase = (w * 2 + mi) * 256;
#pragma unroll
        for (int ni = 0; ni < 2; ni++) {
#pragma unroll
            for (int rg = 0; rg < 4; rg++) {
                int ocb = w * 64 + mi * 32 + 8 * rg + 4 * (l >> 5);
                float4 bb = *(const float4*)&biasE[ocb];
                unsigned d0 = pack_bf16(fmaxf(acc[mi][ni][rg * 4 + 0] + bb.x, 0.f),
                                        fmaxf(acc[mi][ni][rg * 4 + 1] + bb.y, 0.f));
                unsigned d1 = pack_bf16(fmaxf(acc[mi][ni][rg * 4 + 2] + bb.z, 0.f),
                                        fmaxf(acc[mi][ni][rg * 4 + 3] + bb.w, 0.f));
                int unit = kbase + (ni << 7) + ((rg >> 1) << 6) + ((rg & 1) << 5) + (l & 31);
                ((uint2*)Ep)[unit * 2 + (l >> 5)] = make_uint2(d0, d1);
            }
        }
    }
    __syncthreads();

    // ---- phase 3: out GEMM. B = Ep (LDS), A = wOt (L2), rolling prefetch ----
    const int p0 = pt * 64;
    const int hw0 = p0 & 1023;
    const uint4* Ao = (const uint4*)wOt + (size_t)(mt * 20) * 512;

    f32x16 acc2[2][2];
#pragma unroll
    for (int i = 0; i < 2; i++)
#pragma unroll
        for (int j = 0; j < 2; j++)
#pragma unroll
            for (int r = 0; r < 16; r++) acc2[i][j][r] = 0.f;

    uint4 aoc[2][2], boc[2][2];
#pragma unroll
    for (int mi = 0; mi < 2; mi++)
#pragma unroll
        for (int kh = 0; kh < 2; kh++)
            aoc[mi][kh] = Ao[(((mf0 + mi) * 2 + kh) << 6) + l];
#pragma unroll
    for (int ni = 0; ni < 2; ni++)
#pragma unroll
        for (int kh = 0; kh < 2; kh++)
            boc[ni][kh] = Ep[(ni << 7) + (kh << 6) + l];

#pragma unroll 4
    for (int kc = 0; kc < 20; kc++) {
        uint4 aon[2][2], bon[2][2];
        if (kc < 19) {
#pragma unroll
            for (int mi = 0; mi < 2; mi++)
#pragma unroll
                for (int kh = 0; kh < 2; kh++)
                    aon[mi][kh] = Ao[(size_t)(kc + 1) * 512 + (((mf0 + mi) * 2 + kh) << 6) + l];
#pragma unroll
            for (int ni = 0; ni < 2; ni++)
#pragma unroll
                for (int kh = 0; kh < 2; kh++)
                    bon[ni][kh] = Ep[(kc + 1) * 256 + (ni << 7) + (kh << 6) + l];
        }
#pragma unroll
        for (int kh = 0; kh < 2; kh++) {
            acc2[0][0] = __builtin_amdgcn_mfma_f32_32x32x16_bf16(*(short8*)&aoc[0][kh], *(short8*)&boc[0][kh], acc2[0][0], 0, 0, 0);
            acc2[0][1] = __builtin_amdgcn_mfma_f32_32x32x16_bf16(*(short8*)&aoc[0][kh], *(short8*)&boc[1][kh], acc2[0][1], 0, 0, 0);
            acc2[1][0] = __builtin_amdgcn_mfma_f32_32x32x16_bf16(*(short8*)&aoc[1][kh], *(short8*)&boc[0][kh], acc2[1][0], 0, 0, 0);
            acc2[1][1] = __builtin_amdgcn_mfma_f32_32x32x16_bf16(*(short8*)&aoc[1][kh], *(short8*)&boc[1][kh], acc2[1][1], 0, 0, 0);
        }
        if (kc < 19) {
#pragma unroll
            for (int mi = 0; mi < 2; mi++)
#pragma unroll
                for (int kh = 0; kh < 2; kh++) aoc[mi][kh] = aon[mi][kh];
#pragma unroll
            for (int ni = 0; ni < 2; ni++)
#pragma unroll
                for (int kh = 0; kh < 2; kh++) boc[ni][kh] = bon[ni][kh];
        }
    }

#pragma unroll
    for (int mi = 0; mi < 2; mi++)
#pragma unroll
        for (int ni = 0; ni < 2; ni++) {
            int pxl = ni * 32 + (l & 31);
#pragma unroll
            for (int r = 0; r < 16; r++) {
                int oc = w * 64 + mi * 32 + (r & 3) + 8 * (r >> 2) + 4 * (l >> 5);
                out[((size_t)b * 640 + oc) * 1024 + hw0 + pxl] = acc2[mi][ni][r] + biasO[oc];
            }
        }
}

// ===========================================================================
extern "C" void kernel_launch(void* const* d_in, const int* in_sizes, int n_in,
                              void* d_out, int out_size, void* d_ws, size_t ws_size,
                              hipStream_t stream)
{
    const float* x    = (const float*)d_in[0];
    const float* g1   = (const float*)d_in[1];
    const float* b1   = (const float*)d_in[2];
    const float* m1   = (const float*)d_in[3];
    const float* v1   = (const float*)d_in[4];
    const float* w_in = (const float*)d_in[5];
    const float* gi   = (const float*)d_in[6];
    const float* bi   = (const float*)d_in[7];
    const float* mi   = (const float*)d_in[8];
    const float* vi   = (const float*)d_in[9];
    const float* w_emb= (const float*)d_in[10];
    const float* ge   = (const float*)d_in[11];
    const float* be   = (const float*)d_in[12];
    const float* me   = (const float*)d_in[13];
    const float* ve   = (const float*)d_in[14];
    const float* w_out= (const float*)d_in[15];
    const float* go   = (const float*)d_in[16];
    const float* bo   = (const float*)d_in[17];
    const float* mo   = (const float*)d_in[18];
    const float* vo   = (const float*)d_in[19];

    char* ws = (char*)d_ws;
    float*    s1    = (float*)(ws + 0);
    float*    b1c   = (float*)(ws + 2560);
    float*    biasI = (float*)(ws + 5120);
    float*    biasE = (float*)(ws + 5376);
    float*    biasO = (float*)(ws + 7936);
    unsigned* wIt   = (unsigned*)(ws + 16384);
    unsigned* wOt   = (unsigned*)(ws + 98304);
    unsigned* wEt   = (unsigned*)(ws + 917504);   // ends 3,047,424
    float*    out   = (float*)d_out;

    k_prepAll<<<872, 256, 0, stream>>>(g1, b1, m1, v1, w_in, gi, bi, mi, vi,
                                       w_emb, ge, be, me, ve, w_out, go, bo, mo, vo,
                                       s1, b1c, biasI, biasE, biasO, wIt, wEt, wOt);
    k_mega<<<256, 640, 0, stream>>>(x, s1, b1c, wIt, biasI,
                                    wEt, biasE, wOt, biasO, out);
}